// Round 1
// baseline (3490.252 us; speedup 1.0000x reference)
//
#include <hip/hip_runtime.h>
#include <hip/hip_bf16.h>
#include <math.h>

// Problem constants (match reference)
#define NN 100000
#define EE 1250000
#define DD 64

// ---------------- degree count ----------------
__global__ __launch_bounds__(256) void deg_kernel(const int* __restrict__ row,
                                                  float* __restrict__ deg, int E) {
    int e = blockIdx.x * 256 + threadIdx.x;
    if (e >= E) return;
    unsafeAtomicAdd(&deg[row[e]], 1.0f);
}

// ---------------- dis = deg^-0.5 (in-place) ----------------
__global__ __launch_bounds__(256) void dis_kernel(float* __restrict__ deg, int N) {
    int i = blockIdx.x * 256 + threadIdx.x;
    if (i >= N) return;
    float d = deg[i];
    if (d < 0.5f) d += 1.0f;
    deg[i] = 1.0f / sqrtf(d);
}

// ---------------- val[e] = dis[row]*w*dis[col] ----------------
__global__ __launch_bounds__(256) void val_kernel(const int* __restrict__ row,
                                                  const int* __restrict__ col,
                                                  const float* __restrict__ w,
                                                  const float* __restrict__ dis,
                                                  float* __restrict__ val, int E) {
    int e = blockIdx.x * 256 + threadIdx.x;
    if (e >= E) return;
    val[e] = dis[row[e]] * w[e] * dis[col[e]];
}

// ---------------- scalar coefficients ----------------
// layout: [0]=al0*coef1, [1]=al0*coef2, [2..4]=L2 {tmp1_2,tmp2_2,tmp3}, [5..7]=L3
__global__ void coef_kernel(const float* __restrict__ ap, float* __restrict__ coef) {
    if (threadIdx.x != 0 || blockIdx.x != 0) return;
    const float a = 1.0f, b = 1.0f, l = -1.0f, r = 1.0f;
    float als[3];
    als[0] = tanhf(ap[0]);
    als[1] = tanhf(ap[1]);
    als[2] = tanhf(ap[2]);
    float coef1 = (a - b) * 0.5f - (a + b + 2.0f) * 0.5f * ((l + r) / (r - l));
    float coef2 = (a + b + 2.0f) / (r - l);
    coef[0] = als[0] * coef1;
    coef[1] = als[0] * coef2;
    for (int L = 2; L <= 3; ++L) {
        float Lf = (float)L;
        float coef_l     = 2.0f * Lf * (Lf + a + b) * (2.0f * Lf - 2.0f + a + b);
        float coef_lm1_1 = (2.0f * Lf + a + b - 1.0f) * (2.0f * Lf + a + b) * (2.0f * Lf + a + b - 2.0f);
        float coef_lm1_2 = (2.0f * Lf + a + b - 1.0f) * (a * a - b * b);
        float coef_lm2   = 2.0f * (Lf - 1.0f + a) * (Lf - 1.0f + b) * (2.0f * Lf + a + b);
        float tmp1   = als[L - 1] * (coef_lm1_1 / coef_l);
        float tmp2   = als[L - 1] * (coef_lm1_2 / coef_l);
        float tmp3   = als[L - 1] * als[L - 2] * (coef_lm2 / coef_l);
        float tmp1_2 = tmp1 * (2.0f / (r - l));
        float tmp2_2 = tmp1 * ((r + l) / (r - l)) + tmp2;
        int base = 2 + (L - 2) * 3;
        coef[base + 0] = tmp1_2;
        coef[base + 1] = tmp2_2;
        coef[base + 2] = tmp3;
    }
}

// ---------------- SpMM: out[row] += val * h[col], 16 threads/edge ----------------
__global__ __launch_bounds__(256) void spmm_kernel(const int* __restrict__ row,
                                                   const int* __restrict__ col,
                                                   const float* __restrict__ val,
                                                   const float* __restrict__ h,
                                                   float* __restrict__ out, int E) {
    int t = blockIdx.x * 256 + threadIdx.x;
    int e = t >> 4;
    if (e >= E) return;
    int q = t & 15;
    int r = row[e];
    int c = col[e];
    float v = val[e];
    const float4* h4 = (const float4*)h;
    float4 hv = h4[(size_t)c * 16 + q];
    float* o = out + (size_t)r * 64 + q * 4;
    unsafeAtomicAdd(o + 0, v * hv.x);
    unsafeAtomicAdd(o + 1, v * hv.y);
    unsafeAtomicAdd(o + 2, v * hv.z);
    unsafeAtomicAdd(o + 3, v * hv.w);
}

// ---------------- combine L=1: A = c0*x + c1*y ----------------
__global__ __launch_bounds__(256) void comb_first(const float4* __restrict__ x,
                                                  const float4* __restrict__ y,
                                                  float4* __restrict__ outp,
                                                  const float* __restrict__ coef, int n4) {
    int i = blockIdx.x * 256 + threadIdx.x;
    if (i >= n4) return;
    float c0 = coef[0], c1 = coef[1];
    float4 xv = x[i], yv = y[i];
    float4 o;
    o.x = c0 * xv.x + c1 * yv.x;
    o.y = c0 * xv.y + c1 * yv.y;
    o.z = c0 * xv.z + c1 * yv.z;
    o.w = c0 * xv.w + c1 * yv.w;
    outp[i] = o;
}

// ---------------- combine L>=2: out = c0*y - c1*xm1 - c2*xm2 ----------------
__global__ __launch_bounds__(256) void comb_next(const float4* __restrict__ y,
                                                 const float4* __restrict__ xm1,
                                                 const float4* __restrict__ xm2,
                                                 float4* __restrict__ outp,
                                                 const float* __restrict__ coef,
                                                 int cbase, int n4) {
    int i = blockIdx.x * 256 + threadIdx.x;
    if (i >= n4) return;
    float c0 = coef[cbase], c1 = coef[cbase + 1], c2 = coef[cbase + 2];
    float4 yv = y[i], m1 = xm1[i], m2 = xm2[i];
    float4 o;
    o.x = c0 * yv.x - c1 * m1.x - c2 * m2.x;
    o.y = c0 * yv.y - c1 * m1.y - c2 * m2.y;
    o.z = c0 * yv.z - c1 * m1.z - c2 * m2.z;
    o.w = c0 * yv.w - c1 * m1.w - c2 * m2.w;
    outp[i] = o;
}

// ---------------- final fused GEMM: out = [x|A|B|Y] @ W + bias ----------------
// block = 256 (4 waves), each wave owns 4 consecutive rows; W staged in LDS.
__global__ __launch_bounds__(256) void final_gemm(const float* __restrict__ x0,
                                                  const float* __restrict__ x1,
                                                  const float* __restrict__ x2,
                                                  const float* __restrict__ x3,
                                                  const float* __restrict__ W,
                                                  const float* __restrict__ bias,
                                                  float* __restrict__ out) {
    __shared__ float Wl[256 * 64];
    {
        const float4* W4 = (const float4*)W;
        float4* Wl4 = (float4*)Wl;
        for (int i = threadIdx.x; i < 256 * 64 / 4; i += 256) Wl4[i] = W4[i];
    }
    __syncthreads();
    const int lane = threadIdx.x & 63;
    const int wv = threadIdx.x >> 6;
    // wave-uniform base row (force scalar)
    int n0 = __builtin_amdgcn_readfirstlane((int)blockIdx.x * 16 + wv * 4);

    float bval = bias[lane];
    float acc0 = bval, acc1 = bval, acc2 = bval, acc3 = bval;

    #pragma unroll
    for (int seg = 0; seg < 4; ++seg) {
        const float* p = (seg == 0) ? x0 : (seg == 1) ? x1 : (seg == 2) ? x2 : x3;
        const float* r0 = p + (size_t)n0 * 64;
        #pragma unroll
        for (int k = 0; k < 64; ++k) {
            float wval = Wl[(seg * 64 + k) * 64 + lane];
            acc0 += r0[k]       * wval;
            acc1 += r0[64 + k]  * wval;
            acc2 += r0[128 + k] * wval;
            acc3 += r0[192 + k] * wval;
        }
    }
    size_t ob = (size_t)n0 * 64 + lane;
    out[ob]       = acc0;
    out[ob + 64]  = acc1;
    out[ob + 128] = acc2;
    out[ob + 192] = acc3;
}

extern "C" void kernel_launch(void* const* d_in, const int* in_sizes, int n_in,
                              void* d_out, int out_size, void* d_ws, size_t ws_size,
                              hipStream_t stream) {
    const float* x  = (const float*)d_in[0];
    const int*   ei = (const int*)d_in[1];   // int32 (JAX default x64-off) [2, E]
    const float* ew = (const float*)d_in[2];
    const float* ap = (const float*)d_in[3];
    const float* lw = (const float*)d_in[4];
    const float* lb = (const float*)d_in[5];
    float* out = (float*)d_out;

    const int N = NN, E = EE;
    const int ND = N * DD;            // 6.4M floats
    const int n4 = ND / 4;            // 1.6M float4

    const int* row = ei;
    const int* col = ei + E;

    // workspace layout (16B aligned)
    char* ws = (char*)d_ws;
    float* coef = (float*)ws;                          // 256 B reserved
    float* deg  = (float*)(ws + 256);                  // N floats (becomes dis)
    float* val  = (float*)(ws + 256 + (size_t)N * 4);  // E floats
    char*  big  = ws + 256 + (size_t)N * 4 + (size_t)E * 4;
    float* A = (float*)big;
    float* B = (float*)(big + (size_t)ND * 4);
    float* Y = (float*)(big + (size_t)ND * 8);

    const int gridE   = (E + 255) / 256;       // 4883
    const int gridN   = (N + 255) / 256;       // 391
    const int gridSp  = (E * 16) / 256;        // 78125 exact
    const int gridC   = n4 / 256;              // 6250 exact
    const int gridG   = N / 16;                // 6250 exact

    // normalization
    hipMemsetAsync(deg, 0, (size_t)N * 4, stream);
    deg_kernel<<<gridE, 256, 0, stream>>>(row, deg, E);
    coef_kernel<<<1, 64, 0, stream>>>(ap, coef);
    dis_kernel<<<gridN, 256, 0, stream>>>(deg, N);
    val_kernel<<<gridE, 256, 0, stream>>>(row, col, ew, deg, val, E);

    // L = 1
    hipMemsetAsync(Y, 0, (size_t)ND * 4, stream);
    spmm_kernel<<<gridSp, 256, 0, stream>>>(row, col, val, x, Y, E);
    comb_first<<<gridC, 256, 0, stream>>>((const float4*)x, (const float4*)Y,
                                          (float4*)A, coef, n4);
    // L = 2
    hipMemsetAsync(Y, 0, (size_t)ND * 4, stream);
    spmm_kernel<<<gridSp, 256, 0, stream>>>(row, col, val, A, Y, E);
    comb_next<<<gridC, 256, 0, stream>>>((const float4*)Y, (const float4*)A,
                                         (const float4*)x, (float4*)B, coef, 2, n4);
    // L = 3 (result written in-place into Y)
    hipMemsetAsync(Y, 0, (size_t)ND * 4, stream);
    spmm_kernel<<<gridSp, 256, 0, stream>>>(row, col, val, B, Y, E);
    comb_next<<<gridC, 256, 0, stream>>>((const float4*)Y, (const float4*)B,
                                         (const float4*)A, (float4*)Y, coef, 5, n4);

    // out = [x | A | B | Y] @ W + b
    final_gemm<<<gridG, 256, 0, stream>>>(x, A, B, Y, lw, lb, out);
}

// Round 2
// 581.273 us; speedup vs baseline: 6.0045x; 6.0045x over previous
//
#include <hip/hip_runtime.h>
#include <hip/hip_bf16.h>
#include <math.h>

#define NN 100000
#define EE 1250000
#define DD 64

// ---------------- degree count (int atomics) ----------------
__global__ __launch_bounds__(256) void deg_count(const int* __restrict__ row,
                                                 int* __restrict__ degi, int E) {
    int e = blockIdx.x * 256 + threadIdx.x;
    if (e >= E) return;
    atomicAdd(&degi[row[e]], 1);
}

// ---------------- scan step A: per-block exclusive scan + block sums ----------
__global__ __launch_bounds__(256) void scan_a(const int* __restrict__ degi,
                                              int* __restrict__ rowStart,
                                              int* __restrict__ bs, int N) {
    __shared__ int s[256];
    int tid = threadIdx.x;
    int i = blockIdx.x * 256 + tid;
    int v = (i < N) ? degi[i] : 0;
    s[tid] = v;
    __syncthreads();
    for (int off = 1; off < 256; off <<= 1) {
        int t = (tid >= off) ? s[tid - off] : 0;
        __syncthreads();
        s[tid] += t;
        __syncthreads();
    }
    if (i < N) rowStart[i] = s[tid] - v;   // exclusive
    if (tid == 255) bs[blockIdx.x] = s[255];
}

// ---------------- scan step B: exclusive scan of block sums (1 block) --------
__global__ __launch_bounds__(512) void scan_b(int* __restrict__ bs, int nb) {
    __shared__ int s[512];
    int tid = threadIdx.x;
    int v = (tid < nb) ? bs[tid] : 0;
    s[tid] = v;
    __syncthreads();
    for (int off = 1; off < 512; off <<= 1) {
        int t = (tid >= off) ? s[tid - off] : 0;
        __syncthreads();
        s[tid] += t;
        __syncthreads();
    }
    if (tid < nb) bs[tid] = s[tid] - v;    // exclusive
}

// ---------------- scan step C: add block offsets, set rowStart[N]=E ----------
__global__ __launch_bounds__(256) void scan_c(int* __restrict__ rowStart,
                                              const int* __restrict__ bs,
                                              int N, int E) {
    int i = blockIdx.x * 256 + threadIdx.x;
    if (i < N) rowStart[i] += bs[blockIdx.x];
    if (i == 0) rowStart[N] = E;
}

// ---------------- dis = deg^-0.5 (deg==0 -> 1) ----------------
__global__ __launch_bounds__(256) void dis_kernel(const int* __restrict__ degi,
                                                  float* __restrict__ dis, int N) {
    int i = blockIdx.x * 256 + threadIdx.x;
    if (i >= N) return;
    int d = degi[i];
    float df = (d == 0) ? 1.0f : (float)d;
    dis[i] = 1.0f / sqrtf(df);
}

// ---------------- scatter edges into CSR order, pack (val, col) --------------
__global__ __launch_bounds__(256) void scatter_kernel(const int* __restrict__ row,
                                                      const int* __restrict__ col,
                                                      const float* __restrict__ w,
                                                      const float* __restrict__ dis,
                                                      const int* __restrict__ rowStart,
                                                      int* __restrict__ cursor,
                                                      float2* __restrict__ ev, int E) {
    int e = blockIdx.x * 256 + threadIdx.x;
    if (e >= E) return;
    int r = row[e], c = col[e];
    int pos = rowStart[r] + atomicAdd(&cursor[r], 1);
    float v = dis[r] * w[e] * dis[c];
    ev[pos] = make_float2(v, __int_as_float(c));
}

// ---------------- scalar coefficients ----------------
// layout: [0]=al0*coef1, [1]=al0*coef2, [2..4]=L2 {tmp1_2,tmp2_2,tmp3}, [5..7]=L3
__global__ void coef_kernel(const float* __restrict__ ap, float* __restrict__ coef) {
    if (threadIdx.x != 0 || blockIdx.x != 0) return;
    const float a = 1.0f, b = 1.0f, l = -1.0f, r = 1.0f;
    float als[3];
    als[0] = tanhf(ap[0]);
    als[1] = tanhf(ap[1]);
    als[2] = tanhf(ap[2]);
    float coef1 = (a - b) * 0.5f - (a + b + 2.0f) * 0.5f * ((l + r) / (r - l));
    float coef2 = (a + b + 2.0f) / (r - l);
    coef[0] = als[0] * coef1;
    coef[1] = als[0] * coef2;
    for (int L = 2; L <= 3; ++L) {
        float Lf = (float)L;
        float coef_l     = 2.0f * Lf * (Lf + a + b) * (2.0f * Lf - 2.0f + a + b);
        float coef_lm1_1 = (2.0f * Lf + a + b - 1.0f) * (2.0f * Lf + a + b) * (2.0f * Lf + a + b - 2.0f);
        float coef_lm1_2 = (2.0f * Lf + a + b - 1.0f) * (a * a - b * b);
        float coef_lm2   = 2.0f * (Lf - 1.0f + a) * (Lf - 1.0f + b) * (2.0f * Lf + a + b);
        float tmp1   = als[L - 1] * (coef_lm1_1 / coef_l);
        float tmp2   = als[L - 1] * (coef_lm1_2 / coef_l);
        float tmp3   = als[L - 1] * als[L - 2] * (coef_lm2 / coef_l);
        float tmp1_2 = tmp1 * (2.0f / (r - l));
        float tmp2_2 = tmp1 * ((r + l) / (r - l)) + tmp2;
        int base = 2 + (L - 2) * 3;
        coef[base + 0] = tmp1_2;
        coef[base + 1] = tmp2_2;
        coef[base + 2] = tmp3;
    }
}

// ---------------- fused CSR SpMM + combine ----------------
// 16 lanes per row (one float4 each). MODE 0: out = c0*xm1 + c1*Ax
//                                     MODE 1: out = c0*Ax - c1*xm1 - c2*xm2
template <int MODE>
__global__ __launch_bounds__(256) void spmm_fused(const int* __restrict__ rowStart,
                                                  const float2* __restrict__ ev,
                                                  const float4* __restrict__ h,
                                                  const float4* __restrict__ xm1,
                                                  const float4* __restrict__ xm2,
                                                  float4* __restrict__ outp,
                                                  const float* __restrict__ coef,
                                                  int cbase, int N) {
    int t = blockIdx.x * 256 + threadIdx.x;
    int r = t >> 4;
    if (r >= N) return;
    int q = t & 15;
    int s0 = rowStart[r];
    int s1 = rowStart[r + 1];
    float4 acc = make_float4(0.f, 0.f, 0.f, 0.f);
    for (int j = s0; j < s1; ++j) {
        float2 e = ev[j];
        int c = __float_as_int(e.y);
        float4 hv = h[(size_t)c * 16 + q];
        acc.x += e.x * hv.x;
        acc.y += e.x * hv.y;
        acc.z += e.x * hv.z;
        acc.w += e.x * hv.w;
    }
    size_t oi = (size_t)r * 16 + q;
    float4 o;
    if (MODE == 0) {
        float c0 = coef[cbase], c1 = coef[cbase + 1];
        float4 m1 = xm1[oi];
        o.x = c0 * m1.x + c1 * acc.x;
        o.y = c0 * m1.y + c1 * acc.y;
        o.z = c0 * m1.z + c1 * acc.z;
        o.w = c0 * m1.w + c1 * acc.w;
    } else {
        float c0 = coef[cbase], c1 = coef[cbase + 1], c2 = coef[cbase + 2];
        float4 m1 = xm1[oi];
        float4 m2 = xm2[oi];
        o.x = c0 * acc.x - c1 * m1.x - c2 * m2.x;
        o.y = c0 * acc.y - c1 * m1.y - c2 * m2.y;
        o.z = c0 * acc.z - c1 * m1.z - c2 * m2.z;
        o.w = c0 * acc.w - c1 * m1.w - c2 * m2.w;
    }
    outp[oi] = o;
}

// ---------------- final fused GEMM: out = [x|A|B|C] @ W + bias ----------------
__global__ __launch_bounds__(256) void final_gemm(const float* __restrict__ x0,
                                                  const float* __restrict__ x1,
                                                  const float* __restrict__ x2,
                                                  const float* __restrict__ x3,
                                                  const float* __restrict__ W,
                                                  const float* __restrict__ bias,
                                                  float* __restrict__ out) {
    __shared__ float Wl[256 * 64];
    {
        const float4* W4 = (const float4*)W;
        float4* Wl4 = (float4*)Wl;
        for (int i = threadIdx.x; i < 256 * 64 / 4; i += 256) Wl4[i] = W4[i];
    }
    __syncthreads();
    const int lane = threadIdx.x & 63;
    const int wv = threadIdx.x >> 6;
    int n0 = __builtin_amdgcn_readfirstlane((int)blockIdx.x * 16 + wv * 4);

    float bval = bias[lane];
    float acc0 = bval, acc1 = bval, acc2 = bval, acc3 = bval;

    #pragma unroll
    for (int seg = 0; seg < 4; ++seg) {
        const float* p = (seg == 0) ? x0 : (seg == 1) ? x1 : (seg == 2) ? x2 : x3;
        const float* r0 = p + (size_t)n0 * 64;
        #pragma unroll
        for (int k = 0; k < 64; ++k) {
            float wval = Wl[(seg * 64 + k) * 64 + lane];
            acc0 += r0[k]       * wval;
            acc1 += r0[64 + k]  * wval;
            acc2 += r0[128 + k] * wval;
            acc3 += r0[192 + k] * wval;
        }
    }
    size_t ob = (size_t)n0 * 64 + lane;
    out[ob]       = acc0;
    out[ob + 64]  = acc1;
    out[ob + 128] = acc2;
    out[ob + 192] = acc3;
}

extern "C" void kernel_launch(void* const* d_in, const int* in_sizes, int n_in,
                              void* d_out, int out_size, void* d_ws, size_t ws_size,
                              hipStream_t stream) {
    const float* x  = (const float*)d_in[0];
    const int*   ei = (const int*)d_in[1];
    const float* ew = (const float*)d_in[2];
    const float* ap = (const float*)d_in[3];
    const float* lw = (const float*)d_in[4];
    const float* lb = (const float*)d_in[5];
    float* out = (float*)d_out;

    const int N = NN, E = EE;
    const int ND = N * DD;

    const int* row = ei;
    const int* col = ei + E;

    // workspace layout (big 16B-aligned buffers first)
    char* ws = (char*)d_ws;
    float* A   = (float*)ws;                               // 25.6 MB
    float* B   = (float*)(ws + (size_t)ND * 4);            // 25.6 MB
    float* C   = (float*)(ws + (size_t)ND * 8);            // 25.6 MB
    float2* ev = (float2*)(ws + (size_t)ND * 12);          // 10 MB
    char* sm   = ws + (size_t)ND * 12 + (size_t)E * 8;
    float* coef     = (float*)sm;                          // 256 B
    float* dis      = (float*)(sm + 256);                  // N floats
    int*   degi     = (int*)(sm + 256 + (size_t)N * 4);    // N ints (also cursor)
    int*   rowStart = (int*)(sm + 256 + (size_t)N * 8);    // N+1 ints
    int*   bs       = (int*)(sm + 256 + (size_t)N * 12 + 64); // 512 ints

    const int gridE  = (E + 255) / 256;      // 4883
    const int gridN  = (N + 255) / 256;      // 391
    const int gridSp = (N * 16) / 256;       // 6250 exact
    const int gridG  = N / 16;               // 6250 exact

    // ---- CSR build ----
    hipMemsetAsync(degi, 0, (size_t)N * 4, stream);
    deg_count<<<gridE, 256, 0, stream>>>(row, degi, E);
    coef_kernel<<<1, 64, 0, stream>>>(ap, coef);
    scan_a<<<gridN, 256, 0, stream>>>(degi, rowStart, bs, N);
    scan_b<<<1, 512, 0, stream>>>(bs, gridN);
    scan_c<<<gridN, 256, 0, stream>>>(rowStart, bs, N, E);
    dis_kernel<<<gridN, 256, 0, stream>>>(degi, dis, N);
    hipMemsetAsync(degi, 0, (size_t)N * 4, stream);        // reuse as cursor
    scatter_kernel<<<gridE, 256, 0, stream>>>(row, col, ew, dis, rowStart, degi, ev, E);

    // ---- L=1: A = c0*x + c1*(adj@x) ----
    spmm_fused<0><<<gridSp, 256, 0, stream>>>(rowStart, ev, (const float4*)x,
                                              (const float4*)x, (const float4*)x,
                                              (float4*)A, coef, 0, N);
    // ---- L=2: B = c0*(adj@A) - c1*A - c2*x ----
    spmm_fused<1><<<gridSp, 256, 0, stream>>>(rowStart, ev, (const float4*)A,
                                              (const float4*)A, (const float4*)x,
                                              (float4*)B, coef, 2, N);
    // ---- L=3: C = c0*(adj@B) - c1*B - c2*A ----
    spmm_fused<1><<<gridSp, 256, 0, stream>>>(rowStart, ev, (const float4*)B,
                                              (const float4*)B, (const float4*)A,
                                              (float4*)C, coef, 5, N);

    // ---- out = [x | A | B | C] @ W + b ----
    final_gemm<<<gridG, 256, 0, stream>>>(x, A, B, C, lw, lb, out);
}